// Round 14
// baseline (235.425 us; speedup 1.0000x reference)
//
#include <hip/hip_runtime.h>
#include <stdint.h>

// y[m][n] = scales[n] * sum_k x[m][k]*W[n][k] + bias[n]
// M=128, K=4096, N=11008. x fp32; W int8-valued int32 [N][K]; out fp32.
//
// Round-14 = r11 gemm + fused last-block reduce (kills the reduce dispatch):
//   pack_x: x fp32 -> bf16 in MFMA A-frag order into ws; zeroes tickets.
//   gemm8w: 8 waves (512 thr), wave = FULL M (128) x 16 cols -> BN=128.
//           ks=8 -> 688 blocks, cpb=8, 3-buffer LDS ring, counted vmcnt(12)
//           2-deep prefetch -- K-loop byte-identical to r11/r13.
//           Epilogue: store bf16x2 partials, __threadfence, ticket[nt]++;
//           the 8th finisher re-reads all 8 slices (fixed z order, memory
//           values only => deterministic) and writes scales*sum+bias.
//           Fixup overlaps remaining gemm work -> no serial reduce pass.
//   NOTE: no spills tolerated (scratch ops would break hand-counted vmcnt).

#define M_ROWS 128
#define K_DIM  4096
#define N_DIM  11008
#define CHUNKS 64                       // K chunks of 64
#define NT128  (N_DIM / 128)            // 86 block n-tiles
#define KSPLIT 8
#define CPB    (CHUNKS / KSPLIT)        // 8 chunks per block
#define XP_BYTES (M_ROWS * K_DIM * 2)   // 1 MiB packed bf16 x
#define TKT_OFF  XP_BYTES               // 86 ints of ticket counters
#define PART_OFF (XP_BYTES + 512)
#define PART_U32 ((size_t)64 * N_DIM)   // one kz-slice: uint32 per m-pair

typedef __attribute__((ext_vector_type(8))) short bf16x8;
typedef __attribute__((ext_vector_type(4))) float f32x4;
typedef const unsigned __attribute__((address_space(1)))* gas1_t;
typedef unsigned __attribute__((address_space(3)))* las3_t;

__device__ __forceinline__ unsigned bf16_rn(float f) {
  unsigned u = __float_as_uint(f);
  return (u + 0x7FFFu + ((u >> 16) & 1u)) >> 16;   // round-to-nearest-even
}
// two exact int->f32, pack top halves into 2xbf16 (truncate = exact, |w|<=128)
__device__ __forceinline__ unsigned pk2(int a, int b) {
  unsigned lo = __float_as_uint((float)a), hi = __float_as_uint((float)b);
#if __has_builtin(__builtin_amdgcn_perm)
  return __builtin_amdgcn_perm(hi, lo, 0x07060302u);
#else
  return (hi & 0xFFFF0000u) | (lo >> 16);
#endif
}

__device__ __forceinline__ void gload_lds16(const void* g, void* lds) {
#if __has_builtin(__builtin_amdgcn_global_load_lds)
  // generic LDS pointer low 32 bits == LDS byte offset (validated r2-r13)
  __builtin_amdgcn_global_load_lds((gas1_t)g, (las3_t)(size_t)(unsigned)(size_t)lds,
                                   16, 0, 0);
#else
  *(uint4*)lds = *(const uint4*)g;  // synchronous fallback (correct)
#endif
}

// barrier only: LDS buffer hand-off (no new data consumed)
#define BAR()    asm volatile("s_barrier" ::: "memory")
// wait for all but the newest N vmem ops, then barrier. Per-wave waitcnt
// before s_barrier => at barrier exit, every wave's counted DMAs are done.
#define WBAR12() asm volatile("s_waitcnt vmcnt(12)\n\ts_barrier" ::: "memory")
#define WBAR6()  asm volatile("s_waitcnt vmcnt(6)\n\ts_barrier" ::: "memory")
#define WBAR0()  asm volatile("s_waitcnt vmcnt(0)\n\ts_barrier" ::: "memory")

// ---------------- pack x: fp32 -> bf16 in A-frag order ----------------
// Chunk kk = 16 KiB: 16B unit u = (mf*2 + s)*64 + lane
// frag (mf,s): lane l holds x[16*mf + (l&15)][kk*64 + s*32 + 8*(l>>4) + j]
__global__ __launch_bounds__(256) void pack_x_kernel(
    const float* __restrict__ x, unsigned short* __restrict__ xp,
    int* __restrict__ ticket) {
  if (blockIdx.x == 0 && threadIdx.x < NT128) ticket[threadIdx.x] = 0;
  int tid  = blockIdx.x * 256 + threadIdx.x;   // 65536 threads
  int lane = tid & 63;
  int h    = (tid >> 6) & 1;
  int mf   = (tid >> 7) & 7;
  int kk   = tid >> 10;
  int m     = mf * 16 + (lane & 15);
  int kbase = kk * 64 + h * 32 + ((lane >> 4) * 8);
  const float* src = x + (size_t)m * K_DIM + kbase;
  float4 f0 = *(const float4*)(src);
  float4 f1 = *(const float4*)(src + 4);
  float v[8] = {f0.x, f0.y, f0.z, f0.w, f1.x, f1.y, f1.z, f1.w};
  unsigned po[4];
#pragma unroll
  for (int i = 0; i < 4; ++i)
    po[i] = bf16_rn(v[2 * i]) | (bf16_rn(v[2 * i + 1]) << 16);
  *(uint4*)(xp + (size_t)tid * 8) = *(uint4*)po;
}

// ---------------- 8-wave GEMM: block BM=128 x BN=128, cpb=8 chunks ---------
struct BReg { uint4 v[4]; };   // one chunk of B per lane: 16 ints

__global__ __launch_bounds__(512, 4) void gemm8w_kernel(
    const unsigned short* __restrict__ xp,
    const int* __restrict__ wq,
    unsigned* __restrict__ part,
    const float* __restrict__ scales,
    const float* __restrict__ bias,
    float* __restrict__ out,
    int* __restrict__ ticket) {
  __shared__ char As[3 * 16384];       // 3-buffer ring (2 chunks in flight)
  __shared__ int lastLds;

  const int tid  = threadIdx.x;        // 0..511
  const int lane = tid & 63;
  const int w    = tid >> 6;           // wave 0..7 -> cols [16w, 16w+16)
  const int nt   = blockIdx.x;         // 0..85
  const int kz   = blockIdx.y;         // 0..7
  const int kk0  = kz * CPB;
  const size_t n0 = (size_t)nt * 128 + (size_t)w * 16;
  const int l15 = lane & 15, lh = lane >> 4;

  // A staging: 16 KiB/chunk; 512 threads x 2 x 16B, lane-linear
  const char* agp = (const char*)xp + (size_t)kk0 * 16384 + tid * 16;
  // B: row n0 + l15; ints at (kk0+t)*64 + s*32 + lh*8 .. +8
  const int* bptr = wq + (n0 + (size_t)l15) * K_DIM + (size_t)kk0 * 64 + lh * 8;

  f32x4 acc[8];
  {
    f32x4 z = {0.f, 0.f, 0.f, 0.f};
#pragma unroll
    for (int i = 0; i < 8; ++i) acc[i] = z;
  }

  auto STAGE = [&](int t, int bufOff) {
    gload_lds16(agp + (size_t)t * 16384,        As + bufOff + tid * 16);
    gload_lds16(agp + (size_t)t * 16384 + 8192, As + bufOff + tid * 16 + 8192);
  };
  auto LOADB = [&](int t, BReg& R) {
    const int* bp = bptr + t * 64;
    R.v[0] = *(const uint4*)(bp);
    R.v[1] = *(const uint4*)(bp + 4);
    R.v[2] = *(const uint4*)(bp + 32);
    R.v[3] = *(const uint4*)(bp + 36);
  };
  auto COMP = [&](const char* ab, BReg& R) {
    bf16x8 cv[2];
#pragma unroll
    for (int s = 0; s < 2; ++s) {
      union { unsigned u[4]; bf16x8 b; } c;
      c.u[0] = pk2((int)R.v[s * 2].x,     (int)R.v[s * 2].y);
      c.u[1] = pk2((int)R.v[s * 2].z,     (int)R.v[s * 2].w);
      c.u[2] = pk2((int)R.v[s * 2 + 1].x, (int)R.v[s * 2 + 1].y);
      c.u[3] = pk2((int)R.v[s * 2 + 1].z, (int)R.v[s * 2 + 1].w);
      cv[s] = c.b;
    }
#pragma unroll
    for (int mf = 0; mf < 8; ++mf)
#pragma unroll
      for (int s = 0; s < 2; ++s) {
        bf16x8 a = *(const bf16x8*)(ab + (mf * 2 + s) * 1024 + lane * 16);
        acc[mf] = __builtin_amdgcn_mfma_f32_16x16x32_bf16(a, cv[s], acc[mf], 0, 0, 0);
      }
  };

  // phase T: consume chunk T (ring buf T%3, reg R[T%3]); issue chunk T+2 into
  // ring (T+2)%3 (freed at phase T-1). 6 vmem ops/phase (2 DMA + 4 B).
  // Outstanding before WBAR12: chunks T,T+1,T+2 = 18 -> drains chunk T's 6.
#define PHASE(T, CBUF, NBUF, RC, RN)              \
    LOADB((T) + 2, RN);                           \
    BAR();                                        \
    STAGE((T) + 2, (NBUF) * 16384);               \
    WBAR12();                                     \
    COMP(As + (CBUF) * 16384, RC);

  BReg R0, R1, R2;
  // prologue: chunks 0,1 in flight (12 ops)
  STAGE(0, 0);
  LOADB(0, R0);
  STAGE(1, 16384);
  LOADB(1, R1);

#pragma unroll 1
  for (int t = 0; t < 6; t += 3) {       // phases 0..5 (issue chunks 2..7)
    PHASE(t + 0, 0, 2, R0, R2);
    PHASE(t + 1, 1, 0, R1, R0);
    PHASE(t + 2, 2, 1, R2, R1);
  }
  WBAR6();                               // chunk 6 resident (buf0, R0)
  COMP(As + 0 * 16384, R0);
  WBAR0();                               // chunk 7 resident (buf1, R1)
  COMP(As + 1 * 16384, R1);
#undef PHASE

  // bf16x2 partial epilogue, packed along m-pairs:
  // rows mb=mf*16+lh*4 .. +3 ; n = n0 + l15 ; element (mp,n) = rows 2mp,2mp+1
  unsigned* pb = part + (size_t)kz * PART_U32 + n0 + l15;
#pragma unroll
  for (int mf = 0; mf < 8; ++mf) {
    const int mb = mf * 16 + lh * 4;     // even
    unsigned u0 = bf16_rn(acc[mf][0]) | (bf16_rn(acc[mf][1]) << 16);
    unsigned u1 = bf16_rn(acc[mf][2]) | (bf16_rn(acc[mf][3]) << 16);
    pb[(size_t)(mb >> 1) * N_DIM]       = u0;
    pb[(size_t)((mb >> 1) + 1) * N_DIM] = u1;
  }

  // ---- fused reduce: 8th finisher for this nt sums all 8 slices ----
  __threadfence();                       // release partial stores (device)
  if (tid == 0) lastLds = atomicAdd(&ticket[nt], 1);
  __syncthreads();
  if (lastLds != KSPLIT - 1) return;
  __threadfence();                       // acquire other blocks' stores

  // 64 m-pairs x 32 col4-groups = 2048 units; 512 threads x 4 units
#pragma unroll 1
  for (int u = tid; u < 64 * 32; u += 512) {
    const int mp = u >> 5;               // 0..63
    const size_t n = (size_t)nt * 128 + (size_t)(u & 31) * 4;
    float s0[4] = {0.f, 0.f, 0.f, 0.f};
    float s1[4] = {0.f, 0.f, 0.f, 0.f};
#pragma unroll
    for (int z = 0; z < KSPLIT; ++z) {
      uint4 q = *(const uint4*)(part + (size_t)z * PART_U32 + (size_t)mp * N_DIM + n);
      const unsigned uu[4] = {q.x, q.y, q.z, q.w};
#pragma unroll
      for (int j = 0; j < 4; ++j) {
        s0[j] += __uint_as_float(uu[j] << 16);
        s1[j] += __uint_as_float(uu[j] & 0xFFFF0000u);
      }
    }
    float4 sc = *(const float4*)(scales + n);
    float4 bi = *(const float4*)(bias + n);
    const float scv[4] = {sc.x, sc.y, sc.z, sc.w};
    const float biv[4] = {bi.x, bi.y, bi.z, bi.w};
    float4 r0, r1;
    r0.x = scv[0] * s0[0] + biv[0];  r1.x = scv[0] * s1[0] + biv[0];
    r0.y = scv[1] * s0[1] + biv[1];  r1.y = scv[1] * s1[1] + biv[1];
    r0.z = scv[2] * s0[2] + biv[2];  r1.z = scv[2] * s1[2] + biv[2];
    r0.w = scv[3] * s0[3] + biv[3];  r1.w = scv[3] * s1[3] + biv[3];
    *(float4*)(out + (size_t)(2 * mp) * N_DIM + n)     = r0;
    *(float4*)(out + (size_t)(2 * mp + 1) * N_DIM + n) = r1;
  }
}

// ---------------- insurance path if ws is tiny ----------------
__global__ __launch_bounds__(256) void naive_kernel(
    const float* __restrict__ x, const int* __restrict__ wq,
    const float* __restrict__ scales, const float* __restrict__ bias,
    float* __restrict__ out) {
  const int n = blockIdx.x * 256 + threadIdx.x;
  const int m = blockIdx.y;
  const float* xr = x + (size_t)m * K_DIM;
  const int* wr = wq + (size_t)n * K_DIM;
  float s = 0.f;
  for (int k = 0; k < K_DIM; k += 4) {
    float4 xv = *(const float4*)(xr + k);
    int4  wv = *(const int4*)(wr + k);
    s += xv.x * (float)wv.x + xv.y * (float)wv.y +
         xv.z * (float)wv.z + xv.w * (float)wv.w;
  }
  out[(size_t)m * N_DIM + n] = scales[n] * s + bias[n];
}

extern "C" void kernel_launch(void* const* d_in, const int* in_sizes, int n_in,
                              void* d_out, int out_size, void* d_ws, size_t ws_size,
                              hipStream_t stream) {
  const float* x      = (const float*)d_in[0];
  const int* wq       = (const int*)d_in[1];
  const float* scales = (const float*)d_in[2];
  const float* bias   = (const float*)d_in[3];
  float* out          = (float*)d_out;

  const size_t need = (size_t)PART_OFF + (size_t)KSPLIT * PART_U32 * 4;
  if (ws_size < need) {
    naive_kernel<<<dim3(N_DIM / 256, M_ROWS), 256, 0, stream>>>(x, wq, scales, bias, out);
    return;
  }
  unsigned short* xp = (unsigned short*)d_ws;
  int* ticket        = (int*)((char*)d_ws + TKT_OFF);
  unsigned* part     = (unsigned*)((char*)d_ws + PART_OFF);

  pack_x_kernel<<<256, 256, 0, stream>>>(x, xp, ticket);
  gemm8w_kernel<<<dim3(NT128, KSPLIT), 512, 0, stream>>>(
      xp, wq, part, scales, bias, out, ticket);
}

// Round 15
// 51.070 us; speedup vs baseline: 4.6098x; 4.6098x over previous
//
#include <hip/hip_runtime.h>
#include <stdint.h>

// y[m][n] = scales[n] * sum_k x[m][k]*W[n][k] + bias[n]
// M=128, K=4096, N=11008. x fp32; W int8-valued int32 [N][K]; out fp32.
//
// Round-15 = exact revert to round-13 (best verified: 51.5-52.0 us).
//   pack_x: x fp32 -> bf16 in MFMA A-frag order into ws (1 MiB, L2-resident).
//   gemm8w: 8 waves (512 thr), wave = FULL M (128) x 16 cols -> BN=128.
//           B crosses L3 exactly once (176 MB @ ~5.4 TB/s fabric ceiling).
//           ks=8 -> 688 blocks, cpb=8. 3-buffer LDS ring (48 KiB), counted
//           vmcnt 2-deep: 6 vmem ops/phase (2 A-DMA + 4 B) -> vmcnt(12).
//           Partials bf16x2-packed along m-pairs.
//   reduce: out = scales*(sum of 8 bf16 partials) + bias (deterministic).
//   Counter-refuted alternatives: reg-pipelines (r4/r9: allocator
//   de-pipelines, VGPR~56), fused-reduce tail (r14: same de-pipelining,
//   235us), atomics (r10: cross-XCD), M-split (r3: 4x traffic), full-K
//   single pass (r7: 172-CU grid), deeper prefetch (r8: neutral),
//   work-stealing (r12: per-item drain).
//   GOVERNING CONSTRAINT: any extra register pressure in gemm8w flips the
//   allocator into a minimal-VGPR serialized schedule -- keep this kernel
//   minimal; do not add code to it.

#define M_ROWS 128
#define K_DIM  4096
#define N_DIM  11008
#define CHUNKS 64                       // K chunks of 64
#define NT128  (N_DIM / 128)            // 86 block n-tiles
#define KSPLIT 8
#define CPB    (CHUNKS / KSPLIT)        // 8 chunks per block
#define XP_BYTES (M_ROWS * K_DIM * 2)   // 1 MiB packed bf16 x
#define PART_U32 ((size_t)64 * N_DIM)   // one kz-slice: uint32 per m-pair

typedef __attribute__((ext_vector_type(8))) short bf16x8;
typedef __attribute__((ext_vector_type(4))) float f32x4;
typedef const unsigned __attribute__((address_space(1)))* gas1_t;
typedef unsigned __attribute__((address_space(3)))* las3_t;

__device__ __forceinline__ unsigned bf16_rn(float f) {
  unsigned u = __float_as_uint(f);
  return (u + 0x7FFFu + ((u >> 16) & 1u)) >> 16;   // round-to-nearest-even
}
// two exact int->f32, pack top halves into 2xbf16 (truncate = exact, |w|<=128)
__device__ __forceinline__ unsigned pk2(int a, int b) {
  unsigned lo = __float_as_uint((float)a), hi = __float_as_uint((float)b);
#if __has_builtin(__builtin_amdgcn_perm)
  return __builtin_amdgcn_perm(hi, lo, 0x07060302u);
#else
  return (hi & 0xFFFF0000u) | (lo >> 16);
#endif
}

__device__ __forceinline__ void gload_lds16(const void* g, void* lds) {
#if __has_builtin(__builtin_amdgcn_global_load_lds)
  // generic LDS pointer low 32 bits == LDS byte offset (validated r2-r13)
  __builtin_amdgcn_global_load_lds((gas1_t)g, (las3_t)(size_t)(unsigned)(size_t)lds,
                                   16, 0, 0);
#else
  *(uint4*)lds = *(const uint4*)g;  // synchronous fallback (correct)
#endif
}

// barrier only: LDS buffer hand-off (no new data consumed)
#define BAR()    asm volatile("s_barrier" ::: "memory")
// wait for all but the newest N vmem ops, then barrier. Per-wave waitcnt
// before s_barrier => at barrier exit, every wave's counted DMAs are done.
#define WBAR12() asm volatile("s_waitcnt vmcnt(12)\n\ts_barrier" ::: "memory")
#define WBAR6()  asm volatile("s_waitcnt vmcnt(6)\n\ts_barrier" ::: "memory")
#define WBAR0()  asm volatile("s_waitcnt vmcnt(0)\n\ts_barrier" ::: "memory")

// ---------------- pack x: fp32 -> bf16 in A-frag order ----------------
// Chunk kk = 16 KiB: 16B unit u = (mf*2 + s)*64 + lane
// frag (mf,s): lane l holds x[16*mf + (l&15)][kk*64 + s*32 + 8*(l>>4) + j]
__global__ __launch_bounds__(256) void pack_x_kernel(
    const float* __restrict__ x, unsigned short* __restrict__ xp) {
  int tid  = blockIdx.x * 256 + threadIdx.x;   // 65536 threads
  int lane = tid & 63;
  int h    = (tid >> 6) & 1;
  int mf   = (tid >> 7) & 7;
  int kk   = tid >> 10;
  int m     = mf * 16 + (lane & 15);
  int kbase = kk * 64 + h * 32 + ((lane >> 4) * 8);
  const float* src = x + (size_t)m * K_DIM + kbase;
  float4 f0 = *(const float4*)(src);
  float4 f1 = *(const float4*)(src + 4);
  float v[8] = {f0.x, f0.y, f0.z, f0.w, f1.x, f1.y, f1.z, f1.w};
  unsigned po[4];
#pragma unroll
  for (int i = 0; i < 4; ++i)
    po[i] = bf16_rn(v[2 * i]) | (bf16_rn(v[2 * i + 1]) << 16);
  *(uint4*)(xp + (size_t)tid * 8) = *(uint4*)po;
}

// ---------------- 8-wave GEMM: block BM=128 x BN=128, cpb=8 chunks ---------
struct BReg { uint4 v[4]; };   // one chunk of B per lane: 16 ints

__global__ __launch_bounds__(512, 4) void gemm8w_kernel(
    const unsigned short* __restrict__ xp,
    const int* __restrict__ wq,
    unsigned* __restrict__ part) {
  __shared__ char As[3 * 16384];       // 3-buffer ring (2 chunks in flight)

  const int tid  = threadIdx.x;        // 0..511
  const int lane = tid & 63;
  const int w    = tid >> 6;           // wave 0..7 -> cols [16w, 16w+16)
  const int nt   = blockIdx.x;         // 0..85
  const int kz   = blockIdx.y;         // 0..7
  const int kk0  = kz * CPB;
  const size_t n0 = (size_t)nt * 128 + (size_t)w * 16;
  const int l15 = lane & 15, lh = lane >> 4;

  // A staging: 16 KiB/chunk; 512 threads x 2 x 16B, lane-linear
  const char* agp = (const char*)xp + (size_t)kk0 * 16384 + tid * 16;
  // B: row n0 + l15; ints at (kk0+t)*64 + s*32 + lh*8 .. +8
  const int* bptr = wq + (n0 + (size_t)l15) * K_DIM + (size_t)kk0 * 64 + lh * 8;

  f32x4 acc[8];
  {
    f32x4 z = {0.f, 0.f, 0.f, 0.f};
#pragma unroll
    for (int i = 0; i < 8; ++i) acc[i] = z;
  }

  auto STAGE = [&](int t, int bufOff) {
    gload_lds16(agp + (size_t)t * 16384,        As + bufOff + tid * 16);
    gload_lds16(agp + (size_t)t * 16384 + 8192, As + bufOff + tid * 16 + 8192);
  };
  auto LOADB = [&](int t, BReg& R) {
    const int* bp = bptr + t * 64;
    R.v[0] = *(const uint4*)(bp);
    R.v[1] = *(const uint4*)(bp + 4);
    R.v[2] = *(const uint4*)(bp + 32);
    R.v[3] = *(const uint4*)(bp + 36);
  };
  auto COMP = [&](const char* ab, BReg& R) {
    bf16x8 cv[2];
#pragma unroll
    for (int s = 0; s < 2; ++s) {
      union { unsigned u[4]; bf16x8 b; } c;
      c.u[0] = pk2((int)R.v[s * 2].x,     (int)R.v[s * 2].y);
      c.u[1] = pk2((int)R.v[s * 2].z,     (int)R.v[s * 2].w);
      c.u[2] = pk2((int)R.v[s * 2 + 1].x, (int)R.v[s * 2 + 1].y);
      c.u[3] = pk2((int)R.v[s * 2 + 1].z, (int)R.v[s * 2 + 1].w);
      cv[s] = c.b;
    }
#pragma unroll
    for (int mf = 0; mf < 8; ++mf)
#pragma unroll
      for (int s = 0; s < 2; ++s) {
        bf16x8 a = *(const bf16x8*)(ab + (mf * 2 + s) * 1024 + lane * 16);
        acc[mf] = __builtin_amdgcn_mfma_f32_16x16x32_bf16(a, cv[s], acc[mf], 0, 0, 0);
      }
  };

  // phase T: consume chunk T (ring buf T%3, reg R[T%3]); issue chunk T+2 into
  // ring (T+2)%3 (freed at phase T-1). 6 vmem ops/phase (2 DMA + 4 B).
  // Outstanding before WBAR12: chunks T,T+1,T+2 = 18 -> drains chunk T's 6.
#define PHASE(T, CBUF, NBUF, RC, RN)              \
    LOADB((T) + 2, RN);                           \
    BAR();                                        \
    STAGE((T) + 2, (NBUF) * 16384);               \
    WBAR12();                                     \
    COMP(As + (CBUF) * 16384, RC);

  BReg R0, R1, R2;
  // prologue: chunks 0,1 in flight (12 ops)
  STAGE(0, 0);
  LOADB(0, R0);
  STAGE(1, 16384);
  LOADB(1, R1);

#pragma unroll 1
  for (int t = 0; t < 6; t += 3) {       // phases 0..5 (issue chunks 2..7)
    PHASE(t + 0, 0, 2, R0, R2);
    PHASE(t + 1, 1, 0, R1, R0);
    PHASE(t + 2, 2, 1, R2, R1);
  }
  WBAR6();                               // chunk 6 resident (buf0, R0)
  COMP(As + 0 * 16384, R0);
  WBAR0();                               // chunk 7 resident (buf1, R1)
  COMP(As + 1 * 16384, R1);
#undef PHASE

  // bf16x2 partial epilogue, packed along m-pairs:
  // rows mb=mf*16+lh*4 .. +3 ; n = n0 + l15 ; element (mp,n) = rows 2mp,2mp+1
  unsigned* pb = part + (size_t)kz * PART_U32 + n0 + l15;
#pragma unroll
  for (int mf = 0; mf < 8; ++mf) {
    const int mb = mf * 16 + lh * 4;     // even
    unsigned u0 = bf16_rn(acc[mf][0]) | (bf16_rn(acc[mf][1]) << 16);
    unsigned u1 = bf16_rn(acc[mf][2]) | (bf16_rn(acc[mf][3]) << 16);
    pb[(size_t)(mb >> 1) * N_DIM]       = u0;
    pb[(size_t)((mb >> 1) + 1) * N_DIM] = u1;
  }
}

// ---------------- combine bf16 partials + epilogue ----------------
__global__ __launch_bounds__(256) void reduce_kernel(
    const unsigned* __restrict__ part, const float* __restrict__ scales,
    const float* __restrict__ bias, float* __restrict__ out) {
  const int mp = blockIdx.y;                        // 0..63 (m-pair)
  const int c4 = blockIdx.x * 256 + threadIdx.x;
  if (c4 >= N_DIM / 4) return;
  const size_t n = (size_t)c4 * 4;
  float s0[4] = {0.f, 0.f, 0.f, 0.f};
  float s1[4] = {0.f, 0.f, 0.f, 0.f};
#pragma unroll
  for (int z = 0; z < KSPLIT; ++z) {
    uint4 q = *(const uint4*)(part + (size_t)z * PART_U32 + (size_t)mp * N_DIM + n);
    const unsigned uu[4] = {q.x, q.y, q.z, q.w};
#pragma unroll
    for (int j = 0; j < 4; ++j) {
      s0[j] += __uint_as_float(uu[j] << 16);
      s1[j] += __uint_as_float(uu[j] & 0xFFFF0000u);
    }
  }
  float4 sc = *(const float4*)(scales + n);
  float4 bi = *(const float4*)(bias + n);
  const float scv[4] = {sc.x, sc.y, sc.z, sc.w};
  const float biv[4] = {bi.x, bi.y, bi.z, bi.w};
  float4 r0, r1;
  float* o0 = out + (size_t)(2 * mp) * N_DIM + n;
  float* o1 = out + (size_t)(2 * mp + 1) * N_DIM + n;
  r0.x = scv[0] * s0[0] + biv[0];  r1.x = scv[0] * s1[0] + biv[0];
  r0.y = scv[1] * s0[1] + biv[1];  r1.y = scv[1] * s1[1] + biv[1];
  r0.z = scv[2] * s0[2] + biv[2];  r1.z = scv[2] * s1[2] + biv[2];
  r0.w = scv[3] * s0[3] + biv[3];  r1.w = scv[3] * s1[3] + biv[3];
  *(float4*)o0 = r0;
  *(float4*)o1 = r1;
}

// ---------------- insurance path if ws is tiny ----------------
__global__ __launch_bounds__(256) void naive_kernel(
    const float* __restrict__ x, const int* __restrict__ wq,
    const float* __restrict__ scales, const float* __restrict__ bias,
    float* __restrict__ out) {
  const int n = blockIdx.x * 256 + threadIdx.x;
  const int m = blockIdx.y;
  const float* xr = x + (size_t)m * K_DIM;
  const int* wr = wq + (size_t)n * K_DIM;
  float s = 0.f;
  for (int k = 0; k < K_DIM; k += 4) {
    float4 xv = *(const float4*)(xr + k);
    int4  wv = *(const int4*)(wr + k);
    s += xv.x * (float)wv.x + xv.y * (float)wv.y +
         xv.z * (float)wv.z + xv.w * (float)wv.w;
  }
  out[(size_t)m * N_DIM + n] = scales[n] * s + bias[n];
}

extern "C" void kernel_launch(void* const* d_in, const int* in_sizes, int n_in,
                              void* d_out, int out_size, void* d_ws, size_t ws_size,
                              hipStream_t stream) {
  const float* x      = (const float*)d_in[0];
  const int* wq       = (const int*)d_in[1];
  const float* scales = (const float*)d_in[2];
  const float* bias   = (const float*)d_in[3];
  float* out          = (float*)d_out;

  const size_t need = (size_t)XP_BYTES + (size_t)KSPLIT * PART_U32 * 4;
  if (ws_size < need) {
    naive_kernel<<<dim3(N_DIM / 256, M_ROWS), 256, 0, stream>>>(x, wq, scales, bias, out);
    return;
  }
  unsigned short* xp = (unsigned short*)d_ws;
  unsigned* part     = (unsigned*)((char*)d_ws + XP_BYTES);

  pack_x_kernel<<<256, 256, 0, stream>>>(x, xp);
  gemm8w_kernel<<<dim3(NT128, KSPLIT), 512, 0, stream>>>(xp, wq, part);
  reduce_kernel<<<dim3((N_DIM / 4 + 255) / 256, 64), 256, 0, stream>>>(
      part, scales, bias, out);
}